// Round 2
// baseline (9268.099 us; speedup 1.0000x reference)
//
#include <hip/hip_runtime.h>

#define T_STEPS 168
#define B_SZ 512
#define H_SZ 1024
#define IN_SZ 64
#define LAG_SZ 168
#define NWG 256
#define TPB 256

typedef __attribute__((ext_vector_type(8))) short short8;
typedef __attribute__((ext_vector_type(8))) __bf16 bf16x8;
typedef __attribute__((ext_vector_type(4))) float floatx4;

union V8 { short8 s; bf16x8 v; };

__device__ __forceinline__ float bf2f(unsigned short u) {
    union { unsigned u; float f; } v; v.u = ((unsigned)u) << 16; return v.f;
}
__device__ __forceinline__ unsigned short f2bf(float x) {
    union { float f; unsigned u; } v; v.f = x;
    unsigned r = ((v.u >> 16) & 1u) + 0x7fffu;
    return (unsigned short)((v.u + r) >> 16);
}

// W_hh residual (lo part of bf16 pair), fragment-ordered: [tile 64][f=kk*3+ni 96][lane 64][8]
__global__ void crnn_init(const float* __restrict__ Whh,
                          unsigned short* __restrict__ wlo, unsigned int* __restrict__ bar)
{
    int tid = blockIdx.x * blockDim.x + threadIdx.x;
    int nthr = gridDim.x * blockDim.x;
    for (int c = tid; c < 64 * 96 * 64; c += nthr) {
        int lane = c & 63;
        int f = (c >> 6) % 96;
        int tile = c / (96 * 64);
        int kk = f / 3, ni = f % 3;
        int l15 = lane & 15, g4 = lane >> 4;
        int row = ni * H_SZ + tile * 16 + l15;
        int col = kk * 32 + g4 * 8;
        const float* src = Whh + (size_t)row * H_SZ + col;
        short8 s;
        #pragma unroll
        for (int e = 0; e < 8; e++) {
            float v = src[e];
            unsigned short hi = f2bf(v);
            s[e] = (short)f2bf(v - bf2f(hi));
        }
        *(short8*)(wlo + (size_t)c * 8) = s;
    }
    for (int k = tid; k < 256; k += nthr) bar[k] = 0u;
}

__launch_bounds__(TPB, 1)
__global__ void crnn_main(
    const float* __restrict__ lag, const float* __restrict__ curr,
    const float* __restrict__ W1, const float* __restrict__ b1,
    const float* __restrict__ Wih, const float* __restrict__ b_ih,
    const float* __restrict__ Whh, const float* __restrict__ b_hh,
    const float* __restrict__ W3, const float* __restrict__ b3,
    const unsigned short* __restrict__ wlo,
    unsigned short* __restrict__ h_hi, unsigned short* __restrict__ h_lo,
    unsigned int* __restrict__ bar, float* __restrict__ out)
{
    __shared__ __align__(16) unsigned short whi_lds[48 * 1024];  // 96 KB, swizzled
    __shared__ __align__(16) unsigned short wihh_lds[48 * 64];   // 6 KB
    __shared__ __align__(16) unsigned short wihl_lds[48 * 64];   // 6 KB
    __shared__ float red[4];

    const int tid = threadIdx.x;
    const int wid = blockIdx.x;
    const int m = (wid & 7) >> 1;                 // XCD-pair -> batch tile (128 rows)
    const int n = ((wid >> 3) << 1) | (wid & 1);  // 0..63 -> 16 hidden cols
    const int jbase = n * 16;
    const int bbase = m * 128;

    // ---- stage W_hh hi (bf16 of fp32) into LDS, XOR-swizzled byte^=(r&7)<<4 ----
    for (int c = tid; c < 48 * 128; c += TPB) {
        int r = c >> 7, cc = c & 127;
        int gr = (r >> 4) * H_SZ + jbase + (r & 15);
        const float* src = Whh + (size_t)gr * H_SZ + cc * 8;
        short8 s;
        #pragma unroll
        for (int e = 0; e < 8; e++) s[e] = (short)f2bf(src[e]);
        unsigned byte = ((unsigned)(r * 2048 + cc * 16)) ^ ((unsigned)((r & 7) << 4));
        *(short8*)((char*)whi_lds + byte) = s;
    }
    // ---- stage W_ih hi+lo pairs into LDS ----
    for (int c = tid; c < 48 * 8; c += TPB) {
        int r = c >> 3, cc = c & 7;
        int gr = (r >> 4) * H_SZ + jbase + (r & 15);
        const float* src = Wih + (size_t)gr * IN_SZ + cc * 8;
        short8 sh, sl;
        #pragma unroll
        for (int e = 0; e < 8; e++) {
            float v = src[e];
            unsigned short hi = f2bf(v);
            sh[e] = (short)hi;
            sl[e] = (short)f2bf(v - bf2f(hi));
        }
        unsigned byte = ((unsigned)(r * 128 + cc * 16)) ^ ((unsigned)((r & 7) << 4));
        *(short8*)((char*)wihh_lds + byte) = sh;
        *(short8*)((char*)wihl_lds + byte) = sl;
    }

    // ---- h0 = lag @ W1^T + b1 (fp32) -> bf16 pair, buffer 0 ----
    {
        int jl = tid & 15, bg = tid >> 4;
        int jj = jbase + jl;
        int b0 = bbase + bg * 8;
        float a[8];
        float bias = b1[jj];
        #pragma unroll
        for (int i = 0; i < 8; i++) a[i] = bias;
        for (int k = 0; k < LAG_SZ; k += 4) {
            floatx4 wv4 = *(const floatx4*)(W1 + (size_t)jj * LAG_SZ + k);
            #pragma unroll
            for (int i = 0; i < 8; i++) {
                floatx4 lv = *(const floatx4*)(lag + (size_t)(b0 + i) * LAG_SZ + k);
                a[i] += lv.x * wv4.x + lv.y * wv4.y + lv.z * wv4.z + lv.w * wv4.w;
            }
        }
        #pragma unroll
        for (int i = 0; i < 8; i++) {
            unsigned short hi = f2bf(a[i]);
            h_hi[(size_t)(b0 + i) * H_SZ + jj] = hi;
            h_lo[(size_t)(b0 + i) * H_SZ + jj] = f2bf(a[i] - bf2f(hi));
        }
    }

    const int lane = tid & 63;
    const int wv = tid >> 6;
    const int l15 = lane & 15;
    const int g4 = lane >> 4;

    const size_t aoff = (size_t)(bbase + wv * 32 + l15) * H_SZ + g4 * 8;
    const size_t xoff = (size_t)(bbase + wv * 32 + l15) * IN_SZ + g4 * 8;

    unsigned bbyte[3], bswz[3];
    #pragma unroll
    for (int ni = 0; ni < 3; ni++) {
        int r = ni * 16 + l15;
        bbyte[ni] = (unsigned)(r * 2048 + g4 * 16);
        bswz[ni] = (unsigned)((r & 7) << 4);
    }

    const int j = jbase + l15;
    const float br_  = b_ih[j] + b_hh[j];
    const float bz_  = b_ih[H_SZ + j] + b_hh[H_SZ + j];
    const float bni_ = b_ih[2 * H_SZ + j];
    const float bnh_ = b_hh[2 * H_SZ + j];

    const int yb = bbase + n * 2 + (tid >> 7);
    const int ykc = (tid & 127) * 8;
    const floatx4 yw0 = *(const floatx4*)(W3 + ykc);
    const floatx4 yw1 = *(const floatx4*)(W3 + ykc + 4);
    const float b3v = b3[0];

    const unsigned short* wlo_base = wlo + (size_t)n * 49152 + (size_t)lane * 8;

    floatx4 acc_gi[2][3];

    auto compute_gi = [&](int t) {
        const float* xp = curr + (size_t)t * (B_SZ * IN_SZ);
        #pragma unroll
        for (int mi = 0; mi < 2; mi++)
            #pragma unroll
            for (int ni = 0; ni < 3; ni++)
                acc_gi[mi][ni] = floatx4{0.f, 0.f, 0.f, 0.f};
        #pragma unroll
        for (int kg = 0; kg < 2; kg++) {
            #pragma unroll
            for (int mi = 0; mi < 2; mi++) {
                const float* xs = xp + xoff + mi * 16 * IN_SZ + kg * 32;
                floatx4 v0 = *(const floatx4*)(xs);
                floatx4 v1 = *(const floatx4*)(xs + 4);
                V8 ah, al;
                #pragma unroll
                for (int e = 0; e < 8; e++) {
                    float v = (e < 4) ? v0[e] : v1[e - 4];
                    unsigned short hi = f2bf(v);
                    ah.s[e] = (short)hi;
                    al.s[e] = (short)f2bf(v - bf2f(hi));
                }
                #pragma unroll
                for (int ni = 0; ni < 3; ni++) {
                    int r = ni * 16 + l15;
                    unsigned byte = ((unsigned)(r * 128 + kg * 64 + g4 * 16)) ^ ((unsigned)((r & 7) << 4));
                    bf16x8 bh = *(const bf16x8*)((const char*)wihh_lds + byte);
                    bf16x8 bl = *(const bf16x8*)((const char*)wihl_lds + byte);
                    acc_gi[mi][ni] = __builtin_amdgcn_mfma_f32_16x16x32_bf16(ah.v, bh, acc_gi[mi][ni], 0, 0, 0);
                    acc_gi[mi][ni] = __builtin_amdgcn_mfma_f32_16x16x32_bf16(al.v, bh, acc_gi[mi][ni], 0, 0, 0);
                    acc_gi[mi][ni] = __builtin_amdgcn_mfma_f32_16x16x32_bf16(ah.v, bl, acc_gi[mi][ni], 0, 0, 0);
                }
            }
        }
    };

    bool dead = false;  // give-up flag: any barrier timeout -> stop spinning (terminate fast)
    auto barrier_arrive = [&](int s) {
        __syncthreads();
        if (tid == 0) {
            __threadfence();  // agent-scope release: L2 writeback for cross-XCD visibility
            __hip_atomic_fetch_add(&bar[s], 1u, __ATOMIC_RELEASE, __HIP_MEMORY_SCOPE_AGENT);
        }
    };
    auto barrier_wait = [&](int s) {
        if (tid == 0 && !dead) {
            unsigned spins = 0;
            while (__hip_atomic_load(&bar[s], __ATOMIC_RELAXED, __HIP_MEMORY_SCOPE_AGENT) < NWG) {
                __builtin_amdgcn_s_sleep(2);
                if (++spins > 2000000u) { dead = true; break; }
            }
            (void)__hip_atomic_load(&bar[s], __ATOMIC_ACQUIRE, __HIP_MEMORY_SCOPE_AGENT); // inv caches
        }
        __syncthreads();
    };

    auto compute_y = [&](int buf, int tcol) {
        const unsigned short* hh = h_hi + (size_t)buf * (B_SZ * H_SZ) + (size_t)yb * H_SZ + ykc;
        const unsigned short* hl = h_lo + (size_t)buf * (B_SZ * H_SZ) + (size_t)yb * H_SZ + ykc;
        short8 hv = *(const short8*)hh;
        short8 lv = *(const short8*)hl;
        float p = 0.f;
        #pragma unroll
        for (int e = 0; e < 8; e++) {
            float w = (e < 4) ? yw0[e] : yw1[e - 4];
            p += (bf2f((unsigned short)hv[e]) + bf2f((unsigned short)lv[e])) * w;
        }
        #pragma unroll
        for (int s = 32; s >= 1; s >>= 1) p += __shfl_down(p, s, 64);
        if (lane == 0) red[wv] = p;
        __syncthreads();
        if (tid == 0) {
            out[(size_t)(bbase + n * 2 + 0) * T_STEPS + tcol] = red[0] + red[1] + b3v;
            out[(size_t)(bbase + n * 2 + 1) * T_STEPS + tcol] = red[2] + red[3] + b3v;
        }
    };

    barrier_arrive(0);
    compute_gi(0);
    barrier_wait(0);

    for (int t = 0; t < T_STEPS; ++t) {
        const int cb = t & 1, nb = (t + 1) & 1;
        const unsigned short* hch = h_hi + (size_t)cb * (B_SZ * H_SZ);
        const unsigned short* hcl = h_lo + (size_t)cb * (B_SZ * H_SZ);

        if (t > 0) compute_y(cb, t - 1);   // y_{t-1} = W3 . h_t

        floatx4 acc[2][3];
        #pragma unroll
        for (int mi = 0; mi < 2; mi++)
            #pragma unroll
            for (int ni = 0; ni < 3; ni++)
                acc[mi][ni] = floatx4{0.f, 0.f, 0.f, 0.f};

        const unsigned short* abh = hch + aoff;
        const unsigned short* abl = hcl + aoff;
        #pragma unroll
        for (int kk = 0; kk < 32; kk++) {
            bf16x8 a0h = *(const bf16x8*)(abh + kk * 32);
            bf16x8 a0l = *(const bf16x8*)(abl + kk * 32);
            bf16x8 a1h = *(const bf16x8*)(abh + 16 * H_SZ + kk * 32);
            bf16x8 a1l = *(const bf16x8*)(abl + 16 * H_SZ + kk * 32);
            #pragma unroll
            for (int ni = 0; ni < 3; ni++) {
                unsigned byte = (bbyte[ni] + (unsigned)(kk * 64)) ^ bswz[ni];
                bf16x8 bh = *(const bf16x8*)((const char*)whi_lds + byte);
                bf16x8 bl = *(const bf16x8*)(wlo_base + (size_t)(kk * 3 + ni) * 512);
                acc[0][ni] = __builtin_amdgcn_mfma_f32_16x16x32_bf16(a0h, bh, acc[0][ni], 0, 0, 0);
                acc[0][ni] = __builtin_amdgcn_mfma_f32_16x16x32_bf16(a0l, bh, acc[0][ni], 0, 0, 0);
                acc[0][ni] = __builtin_amdgcn_mfma_f32_16x16x32_bf16(a0h, bl, acc[0][ni], 0, 0, 0);
                acc[1][ni] = __builtin_amdgcn_mfma_f32_16x16x32_bf16(a1h, bh, acc[1][ni], 0, 0, 0);
                acc[1][ni] = __builtin_amdgcn_mfma_f32_16x16x32_bf16(a1l, bh, acc[1][ni], 0, 0, 0);
                acc[1][ni] = __builtin_amdgcn_mfma_f32_16x16x32_bf16(a1h, bl, acc[1][ni], 0, 0, 0);
            }
        }

        // ---- gates + state update (fp32), write bf16 pair to buffer nb ----
        unsigned short* nhh = h_hi + (size_t)nb * (B_SZ * H_SZ);
        unsigned short* nhl = h_lo + (size_t)nb * (B_SZ * H_SZ);
        #pragma unroll
        for (int mi = 0; mi < 2; mi++) {
            const int brow = bbase + wv * 32 + mi * 16 + g4 * 4;
            #pragma unroll
            for (int e = 0; e < 4; e++) {
                const int b = brow + e;
                size_t off = (size_t)b * H_SZ + j;
                float gr  = acc[mi][0][e] + acc_gi[mi][0][e] + br_;
                float gz  = acc[mi][1][e] + acc_gi[mi][1][e] + bz_;
                float ghn = acc[mi][2][e] + bnh_;
                float gin = acc_gi[mi][2][e] + bni_;
                float rg = 1.f / (1.f + __expf(-gr));
                float zg = 1.f / (1.f + __expf(-gz));
                float nx = gin + rg * ghn;
                float e2 = __expf(-2.f * fabsf(nx));
                float th = copysignf((1.f - e2) / (1.f + e2), nx);
                float hp = bf2f(hch[off]) + bf2f(hcl[off]);
                float hnew = (1.f - zg) * th + zg * hp;
                unsigned short hi = f2bf(hnew);
                nhh[off] = hi;
                nhl[off] = f2bf(hnew - bf2f(hi));
            }
        }

        barrier_arrive(t + 1);
        if (t + 1 < T_STEPS) compute_gi(t + 1);  // hide gi GEMM in barrier window
        barrier_wait(t + 1);
    }

    compute_y(T_STEPS & 1, T_STEPS - 1);
}

extern "C" void kernel_launch(void* const* d_in, const int* in_sizes, int n_in,
                              void* d_out, int out_size, void* d_ws, size_t ws_size,
                              hipStream_t stream) {
    const float* lag  = (const float*)d_in[0];
    const float* curr = (const float*)d_in[1];
    const float* W1   = (const float*)d_in[2];
    const float* b1   = (const float*)d_in[3];
    const float* Wih  = (const float*)d_in[4];
    const float* bih  = (const float*)d_in[5];
    const float* Whh  = (const float*)d_in[6];
    const float* bhh  = (const float*)d_in[7];
    const float* W3   = (const float*)d_in[8];
    const float* b3   = (const float*)d_in[9];
    float* out = (float*)d_out;

    char* w = (char*)d_ws;
    unsigned short* wlo  = (unsigned short*)(w + 0);         // 64*96*64*8 u16 = 6,291,456 B
    unsigned short* h_hi = (unsigned short*)(w + 6291456);   // 2*512*1024 u16 = 2,097,152 B
    unsigned short* h_lo = (unsigned short*)(w + 8388608);   // 2,097,152 B
    unsigned int*   bar  = (unsigned int*)(w + 10485760);    // 1024 B
    if (ws_size < (size_t)10486784) return;  // clean fail (out stays zero)

    hipLaunchKernelGGL(crnn_init, dim3(1024), dim3(256), 0, stream, Whh, wlo, bar);

    void* args[] = { (void*)&lag, (void*)&curr, (void*)&W1, (void*)&b1,
                     (void*)&Wih, (void*)&bih, (void*)&Whh, (void*)&bhh,
                     (void*)&W3, (void*)&b3, (void*)&wlo, (void*)&h_hi,
                     (void*)&h_lo, (void*)&bar, (void*)&out };
    hipError_t e = hipLaunchCooperativeKernel((void*)crnn_main, dim3(NWG), dim3(TPB), args, 0, stream);
    if (e != hipSuccess) {
        (void)hipGetLastError();  // clear error state
        // Fallback: plain launch. 256 blocks @ 1/CU on 256 CUs are de-facto co-resident;
        // the hand-rolled barrier works under either launch mode.
        hipLaunchKernelGGL(crnn_main, dim3(NWG), dim3(TPB), 0, stream,
                           lag, curr, W1, b1, Wih, bih, Whh, bhh, W3, b3,
                           wlo, h_hi, h_lo, bar, out);
    }
}

// Round 4
// 6839.469 us; speedup vs baseline: 1.3551x; 1.3551x over previous
//
#include <hip/hip_runtime.h>

#define T_STEPS 168
#define B_SZ 512
#define H_SZ 1024
#define IN_SZ 64
#define LAG_SZ 168
#define NWG 256
#define TPB 256

typedef __attribute__((ext_vector_type(8))) short short8;
typedef __attribute__((ext_vector_type(8))) __bf16 bf16x8;
typedef __attribute__((ext_vector_type(4))) float floatx4;

union V8 { short8 s; bf16x8 v; };

__device__ __forceinline__ float bf2f(unsigned short u) {
    union { unsigned u; float f; } v; v.u = ((unsigned)u) << 16; return v.f;
}
__device__ __forceinline__ unsigned short f2bf(float x) {
    union { float f; unsigned u; } v; v.f = x;
    unsigned r = ((v.u >> 16) & 1u) + 0x7fffu;
    return (unsigned short)((v.u + r) >> 16);
}

#define MFB(a, b, c) __builtin_amdgcn_mfma_f32_16x16x32_bf16((a), (b), (c), 0, 0, 0)

// ============================================================================
// ===========================  XCD-LOCAL PATH  ===============================
// ============================================================================
// ws layout (need 16,785,472 B):
//   whi  @ 0         : [64 n16][96 frags(kk*3+g)][64 lanes][8] u16 hi  (6,291,456)
//   wlo  @ 6291456   : same layout, lo residual                         (6,291,456)
//   h_hi @ 12582912  : [2][512][1024] u16                               (2,097,152)
//   h_lo @ 14680064  : [2][512][1024] u16                               (2,097,152)
//   cnt  @ 16777216  : [8][256] u32 barrier counters                    (8,192)
//   pop  @ 16785408  : [16] u32 rank counters                           (64)

__global__ void crnn_init2(const float* __restrict__ Whh,
                           unsigned short* __restrict__ whi, unsigned short* __restrict__ wlo,
                           unsigned short* __restrict__ h_hi, unsigned short* __restrict__ h_lo,
                           unsigned int* __restrict__ cnt, unsigned int* __restrict__ pop)
{
    int tid = blockIdx.x * blockDim.x + threadIdx.x;
    int nthr = gridDim.x * blockDim.x;
    for (int c = tid; c < 64 * 96 * 64; c += nthr) {
        int lane = c & 63;
        int f = (c >> 6) % 96;
        int n16 = c / (96 * 64);
        int kk = f / 3, g = f % 3;
        int l15 = lane & 15, g4 = lane >> 4;
        int row = g * H_SZ + n16 * 16 + l15;
        int col = kk * 32 + g4 * 8;
        const float* src = Whh + (size_t)row * H_SZ + col;
        short8 sh, sl;
        #pragma unroll
        for (int e = 0; e < 8; e++) {
            float v = src[e];
            unsigned short hi = f2bf(v);
            sh[e] = (short)hi;
            sl[e] = (short)f2bf(v - bf2f(hi));
        }
        *(short8*)(whi + (size_t)c * 8) = sh;
        *(short8*)(wlo + (size_t)c * 8) = sl;
    }
    // diagnostic + safety: zero h buffers so any ownership hole reads 0, not garbage
    for (int k = tid; k < 2 * B_SZ * H_SZ; k += nthr) { h_hi[k] = 0; h_lo[k] = 0; }
    for (int k = tid; k < 8 * 256; k += nthr) cnt[k] = 0u;
    for (int k = tid; k < 16; k += nthr) pop[k] = 0u;
}

__launch_bounds__(TPB, 1)
__global__ void crnn_main2(
    const float* __restrict__ lag, const float* __restrict__ curr,
    const float* __restrict__ W1, const float* __restrict__ b1,
    const float* __restrict__ Wih, const float* __restrict__ b_ih,
    const float* __restrict__ Whh, const float* __restrict__ b_hh,
    const float* __restrict__ W3, const float* __restrict__ b3,
    const unsigned short* __restrict__ whi, const unsigned short* __restrict__ wlo,
    unsigned short* __restrict__ h_hi, unsigned short* __restrict__ h_lo,
    unsigned int* __restrict__ cnt, unsigned int* __restrict__ pop,
    float* __restrict__ out)
{
    // ~121 KB LDS -> 1 WG/CU -> exactly 32 WGs per XCD under co-residency.
    __shared__ __align__(16) unsigned short whhA[48 * 1024];   // 96 KB tile-A W_hh hi, swizzled
    __shared__ __align__(16) unsigned short wihh[96 * 64];     // 12 KB W_ih hi
    __shared__ __align__(16) unsigned short wihl[96 * 64];     // 12 KB W_ih lo
    __shared__ float red[4];
    __shared__ int sh_xr[2];

    const int tid = threadIdx.x;
    if (tid == 0) {
        unsigned x;
        asm volatile("s_getreg_b32 %0, hwreg(HW_REG_XCC_ID)" : "=s"(x));
        x &= 7u;
        unsigned rk = __hip_atomic_fetch_add(&pop[x], 1u, __ATOMIC_RELAXED, __HIP_MEMORY_SCOPE_AGENT);
        sh_xr[0] = (int)x;
        sh_xr[1] = (int)(rk & 31u);
    }
    __syncthreads();
    const int xcc = sh_xr[0];
    const int r = sh_xr[1];
    const int RB = xcc * 64;       // this XCD's 64 batch rows
    const int J = r * 32;          // this WG's 32 hidden cols
    const int n16A = 2 * r, n16B = 2 * r + 1;

    const int lane = tid & 63;
    const int wv = tid >> 6;
    const int l15 = lane & 15;
    const int g4 = lane >> 4;

    // ---- stage tile-A W_hh hi (48 rows x 1024) into LDS, XOR-swizzled ----
    for (int c = tid; c < 48 * 128; c += TPB) {
        int rr = c >> 7, cc = c & 127;
        int gr = (rr >> 4) * H_SZ + J + (rr & 15);
        const float* src = Whh + (size_t)gr * H_SZ + cc * 8;
        short8 s;
        #pragma unroll
        for (int e = 0; e < 8; e++) s[e] = (short)f2bf(src[e]);
        unsigned byte = ((unsigned)(rr * 2048 + cc * 16)) ^ ((unsigned)((rr & 7) << 4));
        *(short8*)((char*)whhA + byte) = s;
    }
    // ---- stage W_ih hi+lo (96 rows x 64) ----
    for (int c = tid; c < 96 * 8; c += TPB) {
        int rr = c >> 3, cc = c & 7;
        int gr = (rr >> 5) * H_SZ + J + (rr & 31);
        const float* src = Wih + (size_t)gr * IN_SZ + cc * 8;
        short8 sh, sl;
        #pragma unroll
        for (int e = 0; e < 8; e++) {
            float v = src[e];
            unsigned short hi = f2bf(v);
            sh[e] = (short)hi;
            sl[e] = (short)f2bf(v - bf2f(hi));
        }
        unsigned byte = ((unsigned)(rr * 128 + cc * 16)) ^ ((unsigned)((rr & 7) << 4));
        *(short8*)((char*)wihh + byte) = sh;
        *(short8*)((char*)wihl + byte) = sl;
    }

    // ---- h0 = lag @ W1^T + b1; fp32 master stays in registers ----
    float hp[2][4];
    {
        const int brow = RB + wv * 16 + g4 * 4;
        #pragma unroll
        for (int j16 = 0; j16 < 2; j16++) {
            const int j = J + j16 * 16 + l15;
            float a[4];
            float bias = b1[j];
            #pragma unroll
            for (int e = 0; e < 4; e++) a[e] = bias;
            const float* w1p = W1 + (size_t)j * LAG_SZ;
            for (int k = 0; k < LAG_SZ; k += 4) {
                floatx4 w4 = *(const floatx4*)(w1p + k);
                #pragma unroll
                for (int e = 0; e < 4; e++) {
                    floatx4 l4 = *(const floatx4*)(lag + (size_t)(brow + e) * LAG_SZ + k);
                    a[e] += l4.x * w4.x + l4.y * w4.y + l4.z * w4.z + l4.w * w4.w;
                }
            }
            #pragma unroll
            for (int e = 0; e < 4; e++) {
                hp[j16][e] = a[e];
                unsigned short hi16 = f2bf(a[e]);
                size_t off = (size_t)(brow + e) * H_SZ + j;
                h_hi[off] = hi16;
                h_lo[off] = f2bf(a[e] - bf2f(hi16));
            }
        }
    }

    // loop-invariant gate biases
    float br_[2], bz_[2], bni_[2], bnh_[2];
    #pragma unroll
    for (int j16 = 0; j16 < 2; j16++) {
        int j = J + j16 * 16 + l15;
        br_[j16] = b_ih[j] + b_hh[j];
        bz_[j16] = b_ih[H_SZ + j] + b_hh[H_SZ + j];
        bni_[j16] = b_ih[2 * H_SZ + j];
        bnh_[j16] = b_hh[2 * H_SZ + j];
    }

    // y constants: this WG produces y for rows RB+2r, RB+2r+1
    const int ycol = (tid & 127) * 8;
    const floatx4 yw0 = *(const floatx4*)(W3 + ycol);
    const floatx4 yw1 = *(const floatx4*)(W3 + ycol + 4);
    const float b3v = b3[0];

    // bases for the K-loop
    const unsigned short* sAh = h_hi;
    const unsigned short* sAl = h_lo;
    const char* wfB  = (const char*)whi + (size_t)n16B * 98304 + lane * 16;  // hi, tile B
    const char* wfLA = (const char*)wlo + (size_t)n16A * 98304 + lane * 16;  // lo, tile A
    const char* wfLB = (const char*)wlo + (size_t)n16B * 98304 + lane * 16;  // lo, tile B
    const unsigned voffA0 = (unsigned)(((RB + wv * 16 + l15) * H_SZ + g4 * 8) * 2);

    // LDS B-fragment byte bases (tile A)
    const unsigned bb0 = (unsigned)((0 * 16 + l15) * 2048 + g4 * 16);
    const unsigned bb1 = (unsigned)((1 * 16 + l15) * 2048 + g4 * 16);
    const unsigned bb2 = (unsigned)((2 * 16 + l15) * 2048 + g4 * 16);
    const unsigned swz = (unsigned)((l15 & 7) << 4);

    floatx4 acc_gi[6];

    auto compute_gi = [&](int t) {
        const float* xp = curr + (size_t)t * (B_SZ * IN_SZ)
                        + (size_t)(RB + wv * 16 + l15) * IN_SZ + g4 * 8;
        #pragma unroll
        for (int ni = 0; ni < 6; ni++) acc_gi[ni] = floatx4{0.f, 0.f, 0.f, 0.f};
        #pragma unroll
        for (int kg = 0; kg < 2; kg++) {
            floatx4 v0 = *(const floatx4*)(xp + kg * 32);
            floatx4 v1 = *(const floatx4*)(xp + kg * 32 + 4);
            V8 ah, al;
            #pragma unroll
            for (int e = 0; e < 8; e++) {
                float v = (e < 4) ? v0[e] : v1[e - 4];
                unsigned short hi = f2bf(v);
                ah.s[e] = (short)hi;
                al.s[e] = (short)f2bf(v - bf2f(hi));
            }
            #pragma unroll
            for (int g = 0; g < 3; g++) {
                #pragma unroll
                for (int j16 = 0; j16 < 2; j16++) {
                    int rr = g * 32 + j16 * 16 + l15;
                    unsigned byte = ((unsigned)(rr * 128 + kg * 64 + g4 * 16)) ^ ((unsigned)((rr & 7) << 4));
                    bf16x8 bh = *(const bf16x8*)((const char*)wihh + byte);
                    bf16x8 bl = *(const bf16x8*)((const char*)wihl + byte);
                    int ni = g * 2 + j16;
                    acc_gi[ni] = MFB(ah.v, bh, acc_gi[ni]);
                    acc_gi[ni] = MFB(al.v, bh, acc_gi[ni]);
                    acc_gi[ni] = MFB(ah.v, bl, acc_gi[ni]);
                }
            }
        }
    };

    bool dead = false;
    auto arrive = [&](int s) {
        asm volatile("s_waitcnt vmcnt(0)" ::: "memory");  // h stores -> L2 before signaling
        __syncthreads();
        if (tid == 0)
            __hip_atomic_fetch_add(&cnt[xcc * 256 + s], 1u, __ATOMIC_RELAXED, __HIP_MEMORY_SCOPE_AGENT);
    };
    auto wait_ = [&](int s) {
        if (tid == 0 && !dead) {
            int spins = 0;
            while (__hip_atomic_load(&cnt[xcc * 256 + s], __ATOMIC_RELAXED, __HIP_MEMORY_SCOPE_AGENT) < 32u) {
                __builtin_amdgcn_s_sleep(2);
                if (++spins > 2000000) { dead = true; break; }
            }
        }
        __syncthreads();
    };

    arrive(0);
    compute_gi(0);
    wait_(0);

    int cur = 0;
    for (int t = 0; t < T_STEPS; t++) {
        const unsigned voffA_cur = voffA0 + (unsigned)cur * 1048576u;

        floatx4 acc[6];
        #pragma unroll
        for (int ni = 0; ni < 6; ni++) acc[ni] = floatx4{0.f, 0.f, 0.f, 0.f};

        // ---- K-loop: groups of 2 kk; sc0 A-loads + vmcnt(0) + sched_barrier(0) ----
        for (int g2 = 0; g2 < 16; g2++) {
            V8 Ah0, Al0, Ah1, Al1;
            unsigned va0 = voffA_cur + (unsigned)(g2 * 128);
            unsigned va1 = va0 + 64u;
            asm volatile("global_load_dwordx4 %0, %1, %2 sc0" : "=v"(Ah0.s) : "v"(va0), "s"(sAh));
            asm volatile("global_load_dwordx4 %0, %1, %2 sc0" : "=v"(Al0.s) : "v"(va0), "s"(sAl));
            asm volatile("global_load_dwordx4 %0, %1, %2 sc0" : "=v"(Ah1.s) : "v"(va1), "s"(sAh));
            asm volatile("global_load_dwordx4 %0, %1, %2 sc0" : "=v"(Al1.s) : "v"(va1), "s"(sAl));
            asm volatile("s_waitcnt vmcnt(0)" ::: "memory");
            __builtin_amdgcn_sched_barrier(0);
            #pragma unroll
            for (int q = 0; q < 2; q++) {
                const int kk = g2 * 2 + q;
                const bf16x8 av = (q == 0) ? Ah0.v : Ah1.v;
                const bf16x8 lv = (q == 0) ? Al0.v : Al1.v;
                unsigned o_ = (unsigned)(kk * 64);
                bf16x8 xA0 = *(const bf16x8*)((const char*)whhA + ((bb0 + o_) ^ swz));
                bf16x8 xA1 = *(const bf16x8*)((const char*)whhA + ((bb1 + o_) ^ swz));
                bf16x8 xA2 = *(const bf16x8*)((const char*)whhA + ((bb2 + o_) ^ swz));
                const char* pB  = wfB  + (size_t)kk * 3072;
                const char* pLA = wfLA + (size_t)kk * 3072;
                const char* pLB = wfLB + (size_t)kk * 3072;
                bf16x8 h1_0 = *(const bf16x8*)(pB);
                bf16x8 h1_1 = *(const bf16x8*)(pB + 1024);
                bf16x8 h1_2 = *(const bf16x8*)(pB + 2048);
                bf16x8 l0_0 = *(const bf16x8*)(pLA);
                bf16x8 l0_1 = *(const bf16x8*)(pLA + 1024);
                bf16x8 l0_2 = *(const bf16x8*)(pLA + 2048);
                bf16x8 l1_0 = *(const bf16x8*)(pLB);
                bf16x8 l1_1 = *(const bf16x8*)(pLB + 1024);
                bf16x8 l1_2 = *(const bf16x8*)(pLB + 2048);
                acc[0] = MFB(av, xA0, acc[0]);  acc[0] = MFB(lv, xA0, acc[0]);  acc[0] = MFB(av, l0_0, acc[0]);
                acc[2] = MFB(av, xA1, acc[2]);  acc[2] = MFB(lv, xA1, acc[2]);  acc[2] = MFB(av, l0_1, acc[2]);
                acc[4] = MFB(av, xA2, acc[4]);  acc[4] = MFB(lv, xA2, acc[4]);  acc[4] = MFB(av, l0_2, acc[4]);
                acc[1] = MFB(av, h1_0, acc[1]); acc[1] = MFB(lv, h1_0, acc[1]); acc[1] = MFB(av, l1_0, acc[1]);
                acc[3] = MFB(av, h1_1, acc[3]); acc[3] = MFB(lv, h1_1, acc[3]); acc[3] = MFB(av, l1_1, acc[3]);
                acc[5] = MFB(av, h1_2, acc[5]); acc[5] = MFB(lv, h1_2, acc[5]); acc[5] = MFB(av, l1_2, acc[5]);
            }
        }

        // ---- gates + state update (fp32 master in regs), write pair to next buffer ----
        {
            unsigned short* nh = h_hi + (size_t)(cur ^ 1) * 524288;
            unsigned short* nl = h_lo + (size_t)(cur ^ 1) * 524288;
            const int brow = RB + wv * 16 + g4 * 4;
            #pragma unroll
            for (int j16 = 0; j16 < 2; j16++) {
                const int j = J + j16 * 16 + l15;
                #pragma unroll
                for (int e = 0; e < 4; e++) {
                    float grv = acc[0 + j16][e] + acc_gi[0 + j16][e] + br_[j16];
                    float gzv = acc[2 + j16][e] + acc_gi[2 + j16][e] + bz_[j16];
                    float ghn = acc[4 + j16][e] + bnh_[j16];
                    float gin = acc_gi[4 + j16][e] + bni_[j16];
                    float rg = 1.f / (1.f + __expf(-grv));
                    float zg = 1.f / (1.f + __expf(-gzv));
                    float nx = gin + rg * ghn;
                    float e2 = __expf(-2.f * fabsf(nx));
                    float th = copysignf((1.f - e2) / (1.f + e2), nx);
                    float hnew = (1.f - zg) * th + zg * hp[j16][e];
                    hp[j16][e] = hnew;
                    unsigned short hi16 = f2bf(hnew);
                    size_t off = (size_t)(brow + e) * H_SZ + j;
                    nh[off] = hi16;
                    nl[off] = f2bf(hnew - bf2f(hi16));
                }
            }
        }

        arrive(t + 1);
        if (t + 1 < T_STEPS) compute_gi(t + 1);   // hidden in barrier window
        wait_(t + 1);

        // ---- y_t = W3 . h_{t+1} + b3 (2 rows per WG), sc0 reads of fresh L2 ----
        {
            const int yrow = RB + 2 * r + (tid >> 7);
            const char* ph = (const char*)(h_hi + (size_t)(cur ^ 1) * 524288 + (size_t)yrow * H_SZ + ycol);
            const char* pl = (const char*)(h_lo + (size_t)(cur ^ 1) * 524288 + (size_t)yrow * H_SZ + ycol);
            short8 hv, lv;
            asm volatile("global_load_dwordx4 %0, %1, off sc0" : "=v"(hv) : "v"(ph));
            asm volatile("global_load_dwordx4 %0, %1, off sc0" : "=v"(lv) : "v"(pl));
            asm volatile("s_waitcnt vmcnt(0)" ::: "memory");
            __builtin_amdgcn_sched_barrier(0);
            float p = 0.f;
            #pragma unroll
            for (int e = 0; e < 8; e++) {
                float w = (e < 4) ? yw0[e] : yw1[e - 4];
                p += (bf2f((unsigned short)hv[e]) + bf2f((unsigned short)lv[e])) * w;
            }
            #pragma unroll
            for (int s = 32; s >= 1; s >>= 1) p += __shfl_down(p, s, 64);
            if (lane == 0) red[wv] = p;
            __syncthreads();
            if (tid == 0) {
                out[(size_t)(RB + 2 * r + 0) * T_STEPS + t] = red[0] + red[1] + b3v;
                out[(size_t)(RB + 2 * r + 1) * T_STEPS + t] = red[2] + red[3] + b3v;
            }
            __syncthreads();
        }

        cur ^= 1;
    }
}

// ============================================================================
// =================  LEGACY PATH (round-2, proven, ws 10.5MB) ================
// ============================================================================

__global__ void crnn_init_L(const float* __restrict__ Whh,
                            unsigned short* __restrict__ wlo, unsigned int* __restrict__ bar)
{
    int tid = blockIdx.x * blockDim.x + threadIdx.x;
    int nthr = gridDim.x * blockDim.x;
    for (int c = tid; c < 64 * 96 * 64; c += nthr) {
        int lane = c & 63;
        int f = (c >> 6) % 96;
        int tile = c / (96 * 64);
        int kk = f / 3, ni = f % 3;
        int l15 = lane & 15, g4 = lane >> 4;
        int row = ni * H_SZ + tile * 16 + l15;
        int col = kk * 32 + g4 * 8;
        const float* src = Whh + (size_t)row * H_SZ + col;
        short8 s;
        #pragma unroll
        for (int e = 0; e < 8; e++) {
            float v = src[e];
            unsigned short hi = f2bf(v);
            s[e] = (short)f2bf(v - bf2f(hi));
        }
        *(short8*)(wlo + (size_t)c * 8) = s;
    }
    for (int k = tid; k < 256; k += nthr) bar[k] = 0u;
}

__launch_bounds__(TPB, 1)
__global__ void crnn_main_L(
    const float* __restrict__ lag, const float* __restrict__ curr,
    const float* __restrict__ W1, const float* __restrict__ b1,
    const float* __restrict__ Wih, const float* __restrict__ b_ih,
    const float* __restrict__ Whh, const float* __restrict__ b_hh,
    const float* __restrict__ W3, const float* __restrict__ b3,
    const unsigned short* __restrict__ wlo,
    unsigned short* __restrict__ h_hi, unsigned short* __restrict__ h_lo,
    unsigned int* __restrict__ bar, float* __restrict__ out)
{
    __shared__ __align__(16) unsigned short whi_lds[48 * 1024];
    __shared__ __align__(16) unsigned short wihh_lds[48 * 64];
    __shared__ __align__(16) unsigned short wihl_lds[48 * 64];
    __shared__ float red[4];

    const int tid = threadIdx.x;
    const int wid = blockIdx.x;
    const int m = (wid & 7) >> 1;
    const int n = ((wid >> 3) << 1) | (wid & 1);
    const int jbase = n * 16;
    const int bbase = m * 128;

    for (int c = tid; c < 48 * 128; c += TPB) {
        int rr = c >> 7, cc = c & 127;
        int gr = (rr >> 4) * H_SZ + jbase + (rr & 15);
        const float* src = Whh + (size_t)gr * H_SZ + cc * 8;
        short8 s;
        #pragma unroll
        for (int e = 0; e < 8; e++) s[e] = (short)f2bf(src[e]);
        unsigned byte = ((unsigned)(rr * 2048 + cc * 16)) ^ ((unsigned)((rr & 7) << 4));
        *(short8*)((char*)whi_lds + byte) = s;
    }
    for (int c = tid; c < 48 * 8; c += TPB) {
        int rr = c >> 3, cc = c & 7;
        int gr = (rr >> 4) * H_SZ + jbase + (rr & 15);
        const float* src = Wih + (size_t)gr * IN_SZ + cc * 8;
        short8 sh, sl;
        #pragma unroll
        for (int e = 0; e < 8; e++) {
            float v = src[e];
            unsigned short hi = f2bf(v);
            sh[e] = (short)hi;
            sl[e] = (short)f2bf(v - bf2f(hi));
        }
        unsigned byte = ((unsigned)(rr * 128 + cc * 16)) ^ ((unsigned)((rr & 7) << 4));
        *(short8*)((char*)wihh_lds + byte) = sh;
        *(short8*)((char*)wihl_lds + byte) = sl;
    }

    {
        int jl = tid & 15, bg = tid >> 4;
        int jj = jbase + jl;
        int b0 = bbase + bg * 8;
        float a[8];
        float bias = b1[jj];
        #pragma unroll
        for (int i = 0; i < 8; i++) a[i] = bias;
        for (int k = 0; k < LAG_SZ; k += 4) {
            floatx4 wv4 = *(const floatx4*)(W1 + (size_t)jj * LAG_SZ + k);
            #pragma unroll
            for (int i = 0; i < 8; i++) {
                floatx4 lv = *(const floatx4*)(lag + (size_t)(b0 + i) * LAG_SZ + k);
                a[i] += lv.x * wv4.x + lv.y * wv4.y + lv.z * wv4.z + lv.w * wv4.w;
            }
        }
        #pragma unroll
        for (int i = 0; i < 8; i++) {
            unsigned short hi = f2bf(a[i]);
            h_hi[(size_t)(b0 + i) * H_SZ + jj] = hi;
            h_lo[(size_t)(b0 + i) * H_SZ + jj] = f2bf(a[i] - bf2f(hi));
        }
    }

    const int lane = tid & 63;
    const int wv = tid >> 6;
    const int l15 = lane & 15;
    const int g4 = lane >> 4;

    const size_t aoff = (size_t)(bbase + wv * 32 + l15) * H_SZ + g4 * 8;
    const size_t xoff = (size_t)(bbase + wv * 32 + l15) * IN_SZ + g4 * 8;

    unsigned bbyte[3], bswz[3];
    #pragma unroll
    for (int ni = 0; ni < 3; ni++) {
        int rr = ni * 16 + l15;
        bbyte[ni] = (unsigned)(rr * 2048 + g4 * 16);
        bswz[ni] = (unsigned)((rr & 7) << 4);
    }

    const int j = jbase + l15;
    const float br_ = b_ih[j] + b_hh[j];
    const float bz_ = b_ih[H_SZ + j] + b_hh[H_SZ + j];
    const float bni_ = b_ih[2 * H_SZ + j];
    const float bnh_ = b_hh[2 * H_SZ + j];

    const int yb = bbase + n * 2 + (tid >> 7);
    const int ykc = (tid & 127) * 8;
    const floatx4 yw0 = *(const floatx4*)(W3 + ykc);
    const floatx4 yw1 = *(const floatx4*)(W3 + ykc + 4);
    const float b3v = b3[0];

    const unsigned short* wlo_base = wlo + (size_t)n * 49152 + (size_t)lane * 8;

    floatx4 acc_gi[2][3];

    auto compute_gi = [&](int t) {
        const float* xp = curr + (size_t)t * (B_SZ * IN_SZ);
        #pragma unroll
        for (int mi = 0; mi < 2; mi++)
            #pragma unroll
            for (int ni = 0; ni < 3; ni++)
                acc_gi[mi][ni] = floatx4{0.f, 0.f, 0.f, 0.f};
        #pragma unroll
        for (int kg = 0; kg < 2; kg++) {
            #pragma unroll
            for (int mi = 0; mi < 2; mi++) {
                const float* xs = xp + xoff + mi * 16 * IN_SZ + kg * 32;
                floatx4 v0 = *(const floatx4*)(xs);
                floatx4 v1 = *(const floatx4*)(xs + 4);
                V8 ah, al;
                #pragma unroll
                for (int e = 0; e < 8; e++) {
                    float v = (e < 4) ? v0[e] : v1[e - 4];
                    unsigned short hi = f2bf(v);
                    ah.s[e] = (short)hi;
                    al.s[e] = (short)f2bf(v - bf2f(hi));
                }
                #pragma unroll
                for (int ni = 0; ni < 3; ni++) {
                    int rr = ni * 16 + l15;
                    unsigned byte = ((unsigned)(rr * 128 + kg * 64 + g4 * 16)) ^ ((unsigned)((rr & 7) << 4));
                    bf16x8 bh = *(const bf16x8*)((const char*)wihh_lds + byte);
                    bf16x8 bl = *(const bf16x8*)((const char*)wihl_lds + byte);
                    acc_gi[mi][ni] = MFB(ah.v, bh, acc_gi[mi][ni]);
                    acc_gi[mi][ni] = MFB(al.v, bh, acc_gi[mi][ni]);
                    acc_gi[mi][ni] = MFB(ah.v, bl, acc_gi[mi][ni]);
                }
            }
        }
    };

    bool dead = false;
    auto barrier_arrive = [&](int s) {
        __syncthreads();
        if (tid == 0) {
            __threadfence();
            __hip_atomic_fetch_add(&bar[s], 1u, __ATOMIC_RELEASE, __HIP_MEMORY_SCOPE_AGENT);
        }
    };
    auto barrier_wait = [&](int s) {
        if (tid == 0 && !dead) {
            unsigned spins = 0;
            while (__hip_atomic_load(&bar[s], __ATOMIC_RELAXED, __HIP_MEMORY_SCOPE_AGENT) < NWG) {
                __builtin_amdgcn_s_sleep(2);
                if (++spins > 2000000u) { dead = true; break; }
            }
            (void)__hip_atomic_load(&bar[s], __ATOMIC_ACQUIRE, __HIP_MEMORY_SCOPE_AGENT);
        }
        __syncthreads();
    };

    auto compute_y = [&](int buf, int tcol) {
        const unsigned short* hh = h_hi + (size_t)buf * (B_SZ * H_SZ) + (size_t)yb * H_SZ + ykc;
        const unsigned short* hl = h_lo + (size_t)buf * (B_SZ * H_SZ) + (size_t)yb * H_SZ + ykc;
        short8 hv = *(const short8*)hh;
        short8 lv = *(const short8*)hl;
        float p = 0.f;
        #pragma unroll
        for (int e = 0; e < 8; e++) {
            float w = (e < 4) ? yw0[e] : yw1[e - 4];
            p += (bf2f((unsigned short)hv[e]) + bf2f((unsigned short)lv[e])) * w;
        }
        #pragma unroll
        for (int s = 32; s >= 1; s >>= 1) p += __shfl_down(p, s, 64);
        if (lane == 0) red[wv] = p;
        __syncthreads();
        if (tid == 0) {
            out[(size_t)(bbase + n * 2 + 0) * T_STEPS + tcol] = red[0] + red[1] + b3v;
            out[(size_t)(bbase + n * 2 + 1) * T_STEPS + tcol] = red[2] + red[3] + b3v;
        }
    };

    barrier_arrive(0);
    compute_gi(0);
    barrier_wait(0);

    for (int t = 0; t < T_STEPS; ++t) {
        const int cb = t & 1, nb = (t + 1) & 1;
        const unsigned short* hch = h_hi + (size_t)cb * (B_SZ * H_SZ);
        const unsigned short* hcl = h_lo + (size_t)cb * (B_SZ * H_SZ);

        if (t > 0) compute_y(cb, t - 1);

        floatx4 acc[2][3];
        #pragma unroll
        for (int mi = 0; mi < 2; mi++)
            #pragma unroll
            for (int ni = 0; ni < 3; ni++)
                acc[mi][ni] = floatx4{0.f, 0.f, 0.f, 0.f};

        const unsigned short* abh = hch + aoff;
        const unsigned short* abl = hcl + aoff;
        #pragma unroll
        for (int kk = 0; kk < 32; kk++) {
            bf16x8 a0h = *(const bf16x8*)(abh + kk * 32);
            bf16x8 a0l = *(const bf16x8*)(abl + kk * 32);
            bf16x8 a1h = *(const bf16x8*)(abh + 16 * H_SZ + kk * 32);
            bf16x8 a1l = *(const bf16x8*)(abl + 16 * H_SZ + kk * 32);
            #pragma unroll
            for (int ni = 0; ni < 3; ni++) {
                unsigned byte = (bbyte[ni] + (unsigned)(kk * 64)) ^ bswz[ni];
                bf16x8 bh = *(const bf16x8*)((const char*)whi_lds + byte);
                bf16x8 bl = *(const bf16x8*)(wlo_base + (size_t)(kk * 3 + ni) * 512);
                acc[0][ni] = MFB(a0h, bh, acc[0][ni]);
                acc[0][ni] = MFB(a0l, bh, acc[0][ni]);
                acc[0][ni] = MFB(a0h, bl, acc[0][ni]);
                acc[1][ni] = MFB(a1h, bh, acc[1][ni]);
                acc[1][ni] = MFB(a1l, bh, acc[1][ni]);
                acc[1][ni] = MFB(a1h, bl, acc[1][ni]);
            }
        }

        unsigned short* nhh = h_hi + (size_t)nb * (B_SZ * H_SZ);
        unsigned short* nhl = h_lo + (size_t)nb * (B_SZ * H_SZ);
        #pragma unroll
        for (int mi = 0; mi < 2; mi++) {
            const int brow = bbase + wv * 32 + mi * 16 + g4 * 4;
            #pragma unroll
            for (int e = 0; e < 4; e++) {
                const int b = brow + e;
                size_t off = (size_t)b * H_SZ + j;
                float grv = acc[mi][0][e] + acc_gi[mi][0][e] + br_;
                float gzv = acc[mi][1][e] + acc_gi[mi][1][e] + bz_;
                float ghn = acc[mi][2][e] + bnh_;
                float gin = acc_gi[mi][2][e] + bni_;
                float rg = 1.f / (1.f + __expf(-grv));
                float zg = 1.f / (1.f + __expf(-gzv));
                float nx = gin + rg * ghn;
                float e2 = __expf(-2.f * fabsf(nx));
                float th = copysignf((1.f - e2) / (1.f + e2), nx);
                float hprev = bf2f(hch[off]) + bf2f(hcl[off]);
                float hnew = (1.f - zg) * th + zg * hprev;
                unsigned short hi = f2bf(hnew);
                nhh[off] = hi;
                nhl[off] = f2bf(hnew - bf2f(hi));
            }
        }

        barrier_arrive(t + 1);
        if (t + 1 < T_STEPS) compute_gi(t + 1);
        barrier_wait(t + 1);
    }

    compute_y(T_STEPS & 1, T_STEPS - 1);
}

// ============================================================================

extern "C" void kernel_launch(void* const* d_in, const int* in_sizes, int n_in,
                              void* d_out, int out_size, void* d_ws, size_t ws_size,
                              hipStream_t stream) {
    const float* lag  = (const float*)d_in[0];
    const float* curr = (const float*)d_in[1];
    const float* W1   = (const float*)d_in[2];
    const float* b1   = (const float*)d_in[3];
    const float* Wih  = (const float*)d_in[4];
    const float* bih  = (const float*)d_in[5];
    const float* Whh  = (const float*)d_in[6];
    const float* bhh  = (const float*)d_in[7];
    const float* W3   = (const float*)d_in[8];
    const float* b3   = (const float*)d_in[9];
    float* out = (float*)d_out;
    char* w = (char*)d_ws;

    if (ws_size >= (size_t)16785472) {
        // -------- XCD-local path --------
        unsigned short* whi  = (unsigned short*)(w + 0);
        unsigned short* wlo  = (unsigned short*)(w + 6291456);
        unsigned short* h_hi = (unsigned short*)(w + 12582912);
        unsigned short* h_lo = (unsigned short*)(w + 14680064);
        unsigned int*   cnt  = (unsigned int*)(w + 16777216);
        unsigned int*   pop  = (unsigned int*)(w + 16785408);

        hipLaunchKernelGGL(crnn_init2, dim3(2048), dim3(256), 0, stream,
                           Whh, whi, wlo, h_hi, h_lo, cnt, pop);

        void* args[] = { (void*)&lag, (void*)&curr, (void*)&W1, (void*)&b1,
                         (void*)&Wih, (void*)&bih, (void*)&Whh, (void*)&bhh,
                         (void*)&W3, (void*)&b3, (void*)&whi, (void*)&wlo,
                         (void*)&h_hi, (void*)&h_lo, (void*)&cnt, (void*)&pop, (void*)&out };
        hipError_t e = hipLaunchCooperativeKernel((void*)crnn_main2, dim3(NWG), dim3(TPB), args, 0, stream);
        if (e != hipSuccess) {
            (void)hipGetLastError();
            hipLaunchKernelGGL(crnn_main2, dim3(NWG), dim3(TPB), 0, stream,
                               lag, curr, W1, b1, Wih, bih, Whh, bhh, W3, b3,
                               whi, wlo, h_hi, h_lo, cnt, pop, out);
        }
    } else {
        // -------- legacy round-2 path (proven) --------
        unsigned short* wlo  = (unsigned short*)(w + 0);
        unsigned short* h_hi = (unsigned short*)(w + 6291456);
        unsigned short* h_lo = (unsigned short*)(w + 8388608);
        unsigned int*   bar  = (unsigned int*)(w + 10485760);
        if (ws_size < (size_t)10486784) return;

        hipLaunchKernelGGL(crnn_init_L, dim3(1024), dim3(256), 0, stream, Whh, wlo, bar);

        void* args[] = { (void*)&lag, (void*)&curr, (void*)&W1, (void*)&b1,
                         (void*)&Wih, (void*)&bih, (void*)&Whh, (void*)&bhh,
                         (void*)&W3, (void*)&b3, (void*)&wlo, (void*)&h_hi,
                         (void*)&h_lo, (void*)&bar, (void*)&out };
        hipError_t e = hipLaunchCooperativeKernel((void*)crnn_main_L, dim3(NWG), dim3(TPB), args, 0, stream);
        if (e != hipSuccess) {
            (void)hipGetLastError();
            hipLaunchKernelGGL(crnn_main_L, dim3(NWG), dim3(TPB), 0, stream,
                               lag, curr, W1, b1, Wih, bih, Whh, bhh, W3, b3,
                               wlo, h_hi, h_lo, bar, out);
        }
    }
}

// Round 6
// 2991.280 us; speedup vs baseline: 3.0984x; 2.2865x over previous
//
#include <hip/hip_runtime.h>

#define T_STEPS 168
#define B_SZ 512
#define H_SZ 1024
#define IN_SZ 64
#define LAG_SZ 168
#define NWG 256
#define TPB 256

typedef __attribute__((ext_vector_type(8))) short short8;
typedef __attribute__((ext_vector_type(8))) __bf16 bf16x8;
typedef __attribute__((ext_vector_type(4))) float floatx4;

union V8 { short8 s; bf16x8 v; };

__device__ __forceinline__ float bf2f(unsigned short u) {
    union { unsigned u; float f; } v; v.u = ((unsigned)u) << 16; return v.f;
}
__device__ __forceinline__ unsigned short f2bf(float x) {
    union { float f; unsigned u; } v; v.f = x;
    unsigned r = ((v.u >> 16) & 1u) + 0x7fffu;
    return (unsigned short)((v.u + r) >> 16);
}

#define MFB(a, b, c) __builtin_amdgcn_mfma_f32_16x16x32_bf16((a), (b), (c), 0, 0, 0)

// ============================================================================
// ws layout (need 10,494,016 B; confirmed ws >= 16.8 MB in round 4):
//   whi  @ 0         : [64 n16][96 frags(kk*3+g)][64 lanes][8] u16 hi  (6,291,456)
//   h_hi @ 6291456   : [2][512][1024] u16                               (2,097,152)
//   h_lo @ 8388608   : [2][512][1024] u16                               (2,097,152)
//   cnt  @ 10485760  : [8][256] u32 barrier counters                    (8,192)
//   pop  @ 10493952  : [16] u32 rank counters                           (64)

__global__ void crnn_init2(const float* __restrict__ Whh,
                           unsigned short* __restrict__ whi,
                           unsigned short* __restrict__ h_hi, unsigned short* __restrict__ h_lo,
                           unsigned int* __restrict__ cnt, unsigned int* __restrict__ pop)
{
    int tid = blockIdx.x * blockDim.x + threadIdx.x;
    int nthr = gridDim.x * blockDim.x;
    for (int c = tid; c < 64 * 96 * 64; c += nthr) {
        int lane = c & 63;
        int f = (c >> 6) % 96;
        int n16 = c / (96 * 64);
        int kk = f / 3, g = f % 3;
        int l15 = lane & 15, g4 = lane >> 4;
        int row = g * H_SZ + n16 * 16 + l15;
        int col = kk * 32 + g4 * 8;
        const float* src = Whh + (size_t)row * H_SZ + col;
        short8 sh;
        #pragma unroll
        for (int e = 0; e < 8; e++) sh[e] = (short)f2bf(src[e]);
        *(short8*)(whi + (size_t)c * 8) = sh;
    }
    // safety: zero h buffers so any ownership hole reads 0, not garbage
    for (int k = tid; k < 2 * B_SZ * H_SZ; k += nthr) { h_hi[k] = 0; h_lo[k] = 0; }
    for (int k = tid; k < 8 * 256; k += nthr) cnt[k] = 0u;
    for (int k = tid; k < 16; k += nthr) pop[k] = 0u;
}

__launch_bounds__(TPB, 1)
__global__ void crnn_main2(
    const float* __restrict__ lag, const float* __restrict__ curr,
    const float* __restrict__ W1, const float* __restrict__ b1,
    const float* __restrict__ Wih, const float* __restrict__ b_ih,
    const float* __restrict__ Whh, const float* __restrict__ b_hh,
    const float* __restrict__ W3, const float* __restrict__ b3,
    const unsigned short* __restrict__ whi,
    unsigned short* __restrict__ h_hi, unsigned short* __restrict__ h_lo,
    unsigned int* __restrict__ cnt, unsigned int* __restrict__ pop,
    float* __restrict__ out)
{
    // ~121 KB LDS -> 1 WG/CU -> exactly 32 WGs per XCD under co-residency.
    __shared__ __align__(16) unsigned short whhA[48 * 1024];   // 96 KB tile-A W_hh hi, swizzled
    __shared__ __align__(16) unsigned short wihh[96 * 64];     // 12 KB W_ih hi
    __shared__ __align__(16) unsigned short wihl[96 * 64];     // 12 KB W_ih lo
    __shared__ float red[4];
    __shared__ int sh_xr[2];

    const int tid = threadIdx.x;
    if (tid == 0) {
        unsigned x;
        asm volatile("s_getreg_b32 %0, hwreg(HW_REG_XCC_ID)" : "=s"(x));
        x &= 7u;
        unsigned rk = __hip_atomic_fetch_add(&pop[x], 1u, __ATOMIC_RELAXED, __HIP_MEMORY_SCOPE_AGENT);
        sh_xr[0] = (int)x;
        sh_xr[1] = (int)(rk & 31u);
    }
    __syncthreads();
    const int xcc = sh_xr[0];
    const int r = sh_xr[1];
    const int RB = xcc * 64;       // this XCD's 64 batch rows
    const int J = r * 32;          // this WG's 32 hidden cols
    const int n16B = 2 * r + 1;    // streamed 16-col tile (cols J+16..J+31)

    const int lane = tid & 63;
    const int wv = tid >> 6;
    const int l15 = lane & 15;
    const int g4 = lane >> 4;

    // ---- stage tile-A W_hh hi (48 rows x 1024, cols J..J+15) into LDS, XOR-swizzled ----
    for (int c = tid; c < 48 * 128; c += TPB) {
        int rr = c >> 7, cc = c & 127;
        int gr = (rr >> 4) * H_SZ + J + (rr & 15);
        const float* src = Whh + (size_t)gr * H_SZ + cc * 8;
        short8 s;
        #pragma unroll
        for (int e = 0; e < 8; e++) s[e] = (short)f2bf(src[e]);
        unsigned byte = ((unsigned)(rr * 2048 + cc * 16)) ^ ((unsigned)((rr & 7) << 4));
        *(short8*)((char*)whhA + byte) = s;
    }
    // ---- stage W_ih hi+lo (96 rows x 64) ----
    for (int c = tid; c < 96 * 8; c += TPB) {
        int rr = c >> 3, cc = c & 7;
        int gr = (rr >> 5) * H_SZ + J + (rr & 31);
        const float* src = Wih + (size_t)gr * IN_SZ + cc * 8;
        short8 sh, sl;
        #pragma unroll
        for (int e = 0; e < 8; e++) {
            float v = src[e];
            unsigned short hi = f2bf(v);
            sh[e] = (short)hi;
            sl[e] = (short)f2bf(v - bf2f(hi));
        }
        unsigned byte = ((unsigned)(rr * 128 + cc * 16)) ^ ((unsigned)((rr & 7) << 4));
        *(short8*)((char*)wihh + byte) = sh;
        *(short8*)((char*)wihl + byte) = sl;
    }

    // ---- h0 = lag @ W1^T + b1; fp32 master stays in registers ----
    float hp[2][4];
    {
        const int brow = RB + wv * 16 + g4 * 4;
        #pragma unroll
        for (int j16 = 0; j16 < 2; j16++) {
            const int j = J + j16 * 16 + l15;
            float a[4];
            float bias = b1[j];
            #pragma unroll
            for (int e = 0; e < 4; e++) a[e] = bias;
            const float* w1p = W1 + (size_t)j * LAG_SZ;
            for (int k = 0; k < LAG_SZ; k += 4) {
                floatx4 w4 = *(const floatx4*)(w1p + k);
                #pragma unroll
                for (int e = 0; e < 4; e++) {
                    floatx4 l4 = *(const floatx4*)(lag + (size_t)(brow + e) * LAG_SZ + k);
                    a[e] += l4.x * w4.x + l4.y * w4.y + l4.z * w4.z + l4.w * w4.w;
                }
            }
            #pragma unroll
            for (int e = 0; e < 4; e++) {
                hp[j16][e] = a[e];
                unsigned short hi16 = f2bf(a[e]);
                size_t off = (size_t)(brow + e) * H_SZ + j;
                h_hi[off] = hi16;
                h_lo[off] = f2bf(a[e] - bf2f(hi16));
            }
        }
    }

    // loop-invariant gate biases
    float br_[2], bz_[2], bni_[2], bnh_[2];
    #pragma unroll
    for (int j16 = 0; j16 < 2; j16++) {
        int j = J + j16 * 16 + l15;
        br_[j16] = b_ih[j] + b_hh[j];
        bz_[j16] = b_ih[H_SZ + j] + b_hh[H_SZ + j];
        bni_[j16] = b_ih[2 * H_SZ + j];
        bnh_[j16] = b_hh[2 * H_SZ + j];
    }

    // y constants: this WG produces y for rows RB+2r, RB+2r+1
    const int ycol = (tid & 127) * 8;
    const floatx4 yw0 = *(const floatx4*)(W3 + ycol);
    const floatx4 yw1 = *(const floatx4*)(W3 + ycol + 4);
    const float b3v = b3[0];

    // bases for the K-loop
    const unsigned short* sAh = h_hi;
    const unsigned short* sAl = h_lo;
    const char* wfB = (const char*)whi + (size_t)n16B * 98304 + lane * 16;  // hi, tile B
    const unsigned voffA0 = (unsigned)(((RB + wv * 16 + l15) * H_SZ + g4 * 8) * 2);

    // LDS B-fragment byte bases (tile A)
    const unsigned bb0 = (unsigned)((0 * 16 + l15) * 2048 + g4 * 16);
    const unsigned bb1 = (unsigned)((1 * 16 + l15) * 2048 + g4 * 16);
    const unsigned bb2 = (unsigned)((2 * 16 + l15) * 2048 + g4 * 16);
    const unsigned swz = (unsigned)((l15 & 7) << 4);

    floatx4 acc_gi[6];

    auto compute_gi = [&](int t) {
        const float* xp = curr + (size_t)t * (B_SZ * IN_SZ)
                        + (size_t)(RB + wv * 16 + l15) * IN_SZ + g4 * 8;
        #pragma unroll
        for (int ni = 0; ni < 6; ni++) acc_gi[ni] = floatx4{0.f, 0.f, 0.f, 0.f};
        #pragma unroll
        for (int kg = 0; kg < 2; kg++) {
            floatx4 v0 = *(const floatx4*)(xp + kg * 32);
            floatx4 v1 = *(const floatx4*)(xp + kg * 32 + 4);
            V8 ah, al;
            #pragma unroll
            for (int e = 0; e < 8; e++) {
                float v = (e < 4) ? v0[e] : v1[e - 4];
                unsigned short hi = f2bf(v);
                ah.s[e] = (short)hi;
                al.s[e] = (short)f2bf(v - bf2f(hi));
            }
            #pragma unroll
            for (int g = 0; g < 3; g++) {
                #pragma unroll
                for (int j16 = 0; j16 < 2; j16++) {
                    int rr = g * 32 + j16 * 16 + l15;
                    unsigned byte = ((unsigned)(rr * 128 + kg * 64 + g4 * 16)) ^ ((unsigned)((rr & 7) << 4));
                    bf16x8 bh = *(const bf16x8*)((const char*)wihh + byte);
                    bf16x8 bl = *(const bf16x8*)((const char*)wihl + byte);
                    int ni = g * 2 + j16;
                    acc_gi[ni] = MFB(ah.v, bh, acc_gi[ni]);
                    acc_gi[ni] = MFB(al.v, bh, acc_gi[ni]);
                    acc_gi[ni] = MFB(ah.v, bl, acc_gi[ni]);
                }
            }
        }
    };

    bool dead = false;
    auto arrive = [&](int s) {
        asm volatile("s_waitcnt vmcnt(0)" ::: "memory");  // h stores -> L2 before signaling
        __syncthreads();
        if (tid == 0)
            __hip_atomic_fetch_add(&cnt[xcc * 256 + s], 1u, __ATOMIC_RELAXED, __HIP_MEMORY_SCOPE_AGENT);
    };
    auto wait_ = [&](int s) {
        if (tid == 0 && !dead) {
            int spins = 0;
            while (__hip_atomic_load(&cnt[xcc * 256 + s], __ATOMIC_RELAXED, __HIP_MEMORY_SCOPE_AGENT) < 32u) {
                __builtin_amdgcn_s_sleep(2);
                if (++spins > 2000000) { dead = true; break; }
            }
        }
        __syncthreads();
    };

    arrive(0);
    compute_gi(0);
    wait_(0);

    int cur = 0;
    for (int t = 0; t < T_STEPS; t++) {
        const unsigned voffA_cur = voffA0 + (unsigned)cur * 1048576u;

        floatx4 acc[6];
        #pragma unroll
        for (int ni = 0; ni < 6; ni++) acc[ni] = floatx4{0.f, 0.f, 0.f, 0.f};

        // ---- K-loop: groups of 4 kk; 8 sc0 A-loads + vmcnt(0) + sched_barrier(0) ----
        for (int g4i = 0; g4i < 8; g4i++) {
            V8 Ah0, Al0, Ah1, Al1, Ah2, Al2, Ah3, Al3;
            unsigned va = voffA_cur + (unsigned)(g4i * 256);
            asm volatile("global_load_dwordx4 %0, %1, %2 sc0" : "=v"(Ah0.s) : "v"(va), "s"(sAh));
            asm volatile("global_load_dwordx4 %0, %1, %2 sc0" : "=v"(Al0.s) : "v"(va), "s"(sAl));
            asm volatile("global_load_dwordx4 %0, %1, %2 offset:64 sc0"  : "=v"(Ah1.s) : "v"(va), "s"(sAh));
            asm volatile("global_load_dwordx4 %0, %1, %2 offset:64 sc0"  : "=v"(Al1.s) : "v"(va), "s"(sAl));
            asm volatile("global_load_dwordx4 %0, %1, %2 offset:128 sc0" : "=v"(Ah2.s) : "v"(va), "s"(sAh));
            asm volatile("global_load_dwordx4 %0, %1, %2 offset:128 sc0" : "=v"(Al2.s) : "v"(va), "s"(sAl));
            asm volatile("global_load_dwordx4 %0, %1, %2 offset:192 sc0" : "=v"(Ah3.s) : "v"(va), "s"(sAh));
            asm volatile("global_load_dwordx4 %0, %1, %2 offset:192 sc0" : "=v"(Al3.s) : "v"(va), "s"(sAl));
            asm volatile("s_waitcnt vmcnt(0)" ::: "memory");
            __builtin_amdgcn_sched_barrier(0);
            #pragma unroll
            for (int q = 0; q < 4; q++) {
                const int kk = g4i * 4 + q;
                const bf16x8 av = (q == 0) ? Ah0.v : (q == 1) ? Ah1.v : (q == 2) ? Ah2.v : Ah3.v;
                const bf16x8 lv = (q == 0) ? Al0.v : (q == 1) ? Al1.v : (q == 2) ? Al2.v : Al3.v;
                unsigned o_ = (unsigned)(kk * 64);
                bf16x8 xA0 = *(const bf16x8*)((const char*)whhA + ((bb0 + o_) ^ swz));
                bf16x8 xA1 = *(const bf16x8*)((const char*)whhA + ((bb1 + o_) ^ swz));
                bf16x8 xA2 = *(const bf16x8*)((const char*)whhA + ((bb2 + o_) ^ swz));
                const char* pB = wfB + (size_t)kk * 3072;
                bf16x8 h1_0 = *(const bf16x8*)(pB);
                bf16x8 h1_1 = *(const bf16x8*)(pB + 1024);
                bf16x8 h1_2 = *(const bf16x8*)(pB + 2048);
                acc[0] = MFB(av, xA0, acc[0]);   acc[0] = MFB(lv, xA0, acc[0]);
                acc[2] = MFB(av, xA1, acc[2]);   acc[2] = MFB(lv, xA1, acc[2]);
                acc[4] = MFB(av, xA2, acc[4]);   acc[4] = MFB(lv, xA2, acc[4]);
                acc[1] = MFB(av, h1_0, acc[1]);  acc[1] = MFB(lv, h1_0, acc[1]);
                acc[3] = MFB(av, h1_1, acc[3]);  acc[3] = MFB(lv, h1_1, acc[3]);
                acc[5] = MFB(av, h1_2, acc[5]);  acc[5] = MFB(lv, h1_2, acc[5]);
            }
        }

        // ---- gates + state update (fp32 master in regs), write pair to next buffer ----
        {
            unsigned short* nh = h_hi + (size_t)(cur ^ 1) * 524288;
            unsigned short* nl = h_lo + (size_t)(cur ^ 1) * 524288;
            const int brow = RB + wv * 16 + g4 * 4;
            #pragma unroll
            for (int j16 = 0; j16 < 2; j16++) {
                const int j = J + j16 * 16 + l15;
                #pragma unroll
                for (int e = 0; e < 4; e++) {
                    float grv = acc[0 + j16][e] + acc_gi[0 + j16][e] + br_[j16];
                    float gzv = acc[2 + j16][e] + acc_gi[2 + j16][e] + bz_[j16];
                    float ghn = acc[4 + j16][e] + bnh_[j16];
                    float gin = acc_gi[4 + j16][e] + bni_[j16];
                    float rg = 1.f / (1.f + __expf(-grv));
                    float zg = 1.f / (1.f + __expf(-gzv));
                    float nx = gin + rg * ghn;
                    float e2 = __expf(-2.f * fabsf(nx));
                    float th = copysignf((1.f - e2) / (1.f + e2), nx);
                    float hnew = (1.f - zg) * th + zg * hp[j16][e];
                    hp[j16][e] = hnew;
                    unsigned short hi16 = f2bf(hnew);
                    size_t off = (size_t)(brow + e) * H_SZ + j;
                    nh[off] = hi16;
                    nl[off] = f2bf(hnew - bf2f(hi16));
                }
            }
        }

        arrive(t + 1);
        if (t + 1 < T_STEPS) compute_gi(t + 1);   // hidden in barrier window
        wait_(t + 1);

        // ---- y_t = W3 . h_{t+1} + b3 (2 rows per WG), sc0 reads of fresh L2 ----
        {
            const int yrow = RB + 2 * r + (tid >> 7);
            const char* ph = (const char*)(h_hi + (size_t)(cur ^ 1) * 524288 + (size_t)yrow * H_SZ + ycol);
            const char* pl = (const char*)(h_lo + (size_t)(cur ^ 1) * 524288 + (size_t)yrow * H_SZ + ycol);
            short8 hv, lv;
            asm volatile("global_load_dwordx4 %0, %1, off sc0" : "=v"(hv) : "v"(ph));
            asm volatile("global_load_dwordx4 %0, %1, off sc0" : "=v"(lv) : "v"(pl));
            asm volatile("s_waitcnt vmcnt(0)" ::: "memory");
            __builtin_amdgcn_sched_barrier(0);
            float p = 0.f;
            #pragma unroll
            for (int e = 0; e < 8; e++) {
                float w = (e < 4) ? yw0[e] : yw1[e - 4];
                p += (bf2f((unsigned short)hv[e]) + bf2f((unsigned short)lv[e])) * w;
            }
            #pragma unroll
            for (int s = 32; s >= 1; s >>= 1) p += __shfl_down(p, s, 64);
            if (lane == 0) red[wv] = p;
            __syncthreads();
            if (tid == 0) {
                out[(size_t)(RB + 2 * r + 0) * T_STEPS + t] = red[0] + red[1] + b3v;
                out[(size_t)(RB + 2 * r + 1) * T_STEPS + t] = red[2] + red[3] + b3v;
            }
            __syncthreads();
        }

        cur ^= 1;
    }
}

// ============================================================================

extern "C" void kernel_launch(void* const* d_in, const int* in_sizes, int n_in,
                              void* d_out, int out_size, void* d_ws, size_t ws_size,
                              hipStream_t stream) {
    const float* lag  = (const float*)d_in[0];
    const float* curr = (const float*)d_in[1];
    const float* W1   = (const float*)d_in[2];
    const float* b1   = (const float*)d_in[3];
    const float* Wih  = (const float*)d_in[4];
    const float* bih  = (const float*)d_in[5];
    const float* Whh  = (const float*)d_in[6];
    const float* bhh  = (const float*)d_in[7];
    const float* W3   = (const float*)d_in[8];
    const float* b3   = (const float*)d_in[9];
    float* out = (float*)d_out;
    char* w = (char*)d_ws;

    if (ws_size < (size_t)10494016) return;  // clean fail; known ws >= 16.8 MB

    unsigned short* whi  = (unsigned short*)(w + 0);
    unsigned short* h_hi = (unsigned short*)(w + 6291456);
    unsigned short* h_lo = (unsigned short*)(w + 8388608);
    unsigned int*   cnt  = (unsigned int*)(w + 10485760);
    unsigned int*   pop  = (unsigned int*)(w + 10493952);

    hipLaunchKernelGGL(crnn_init2, dim3(2048), dim3(256), 0, stream,
                       Whh, whi, h_hi, h_lo, cnt, pop);

    void* args[] = { (void*)&lag, (void*)&curr, (void*)&W1, (void*)&b1,
                     (void*)&Wih, (void*)&bih, (void*)&Whh, (void*)&bhh,
                     (void*)&W3, (void*)&b3, (void*)&whi,
                     (void*)&h_hi, (void*)&h_lo, (void*)&cnt, (void*)&pop, (void*)&out };
    hipError_t e = hipLaunchCooperativeKernel((void*)crnn_main2, dim3(NWG), dim3(TPB), args, 0, stream);
    if (e != hipSuccess) {
        (void)hipGetLastError();
        hipLaunchKernelGGL(crnn_main2, dim3(NWG), dim3(TPB), 0, stream,
                           lag, curr, W1, b1, Wih, bih, Whh, bhh, W3, b3,
                           whi, h_hi, h_lo, cnt, pop, out);
    }
}